// Round 2
// baseline (695.446 us; speedup 1.0000x reference)
//
#include <hip/hip_runtime.h>
#include <hip/hip_bf16.h>
#include <stdint.h>

typedef unsigned int u32;
typedef unsigned short u16;

__device__ __forceinline__ float bf2f(u16 u) {
    union { u32 u; float f; } v; v.u = ((u32)u) << 16; return v.f;
}
__device__ __forceinline__ u16 f2bf(float f) {
    u32 u = __float_as_uint(f);
    u32 r = (u + 0x7FFFu + ((u >> 16) & 1u)) >> 16;  // RNE
    return (u16)r;
}

// flags[0] = 1 if external float tensors are f32 (else packed bf16)
// flags[1] = 1 if edge_index is int64 (else int32)
__global__ __launch_bounds__(256) void detect_k(const u32* __restrict__ xw,
                                                const u32* __restrict__ ew,
                                                int* __restrict__ flags) {
    __shared__ int cnt;
    __shared__ u32 orr;
    int t = threadIdx.x;
    if (t == 0) { cnt = 0; orr = 0u; }
    __syncthreads();
    int hits = 0;
    for (int i = t; i < 1024; i += 256) {
        u32 f = (xw[i] >> 7) & 0xFFu;     // bf16-packed: low-half exp field; f32: mantissa bits
        if (f >= 100u && f <= 140u) hits++;
    }
    atomicAdd(&cnt, hits);
    atomicOr(&orr, ew[2 * t + 1]);        // hi-words if int64 (all 0), else edge values
    __syncthreads();
    if (t == 0) {
        flags[0] = (cnt < 512) ? 1 : 0;
        flags[1] = (orr == 0u) ? 1 : 0;
    }
}

__global__ __launch_bounds__(256) void count_deg_k(const void* __restrict__ ei, int E,
                                                   const int* __restrict__ flags,
                                                   int* __restrict__ deg) {
    int i = blockIdx.x * 256 + threadIdx.x;
    if (i >= E) return;
    int d = flags[1] ? (int)((const long long*)ei)[E + i] : ((const int*)ei)[E + i];
    atomicAdd(&deg[d], 1);
}

// single-block scan: off = exclusive-prefix(deg), cursor = off, dinv = rsqrt(deg+1)
__global__ __launch_bounds__(1024) void scan_k(const int* __restrict__ deg,
                                               int* __restrict__ off, int* __restrict__ cursor,
                                               float* __restrict__ dinv, int M) {
    __shared__ int buf[2][1024];
    const int t = threadIdx.x;
    const int chunk = (M + 1023) / 1024;
    const int lo = t * chunk;
    const int hi = min(lo + chunk, M);
    int s = 0;
    for (int i = lo; i < hi; i++) s += deg[i];
    buf[0][t] = s;
    __syncthreads();
    int cur = 0;
    for (int d = 1; d < 1024; d <<= 1) {
        int v = buf[cur][t];
        if (t >= d) v += buf[cur][t - d];
        buf[cur ^ 1][t] = v;
        __syncthreads();
        cur ^= 1;
    }
    int base = buf[cur][t] - s;  // exclusive prefix
    for (int i = lo; i < hi; i++) {
        off[i] = base;
        cursor[i] = base;
        int d = deg[i];
        dinv[i] = rsqrtf((float)(d + 1));  // +1 self-loop
        base += d;
    }
    if (t == 1023) off[M] = buf[cur][1023];
}

__global__ __launch_bounds__(256) void fill_k(const void* __restrict__ ei, int E,
                                              const int* __restrict__ flags,
                                              int* __restrict__ cursor, int* __restrict__ eidx) {
    int i = blockIdx.x * 256 + threadIdx.x;
    if (i >= E) return;
    int s, d;
    if (flags[1]) { const long long* p = (const long long*)ei; s = (int)p[i]; d = (int)p[E + i]; }
    else          { const int* p = (const int*)ei;             s = p[i];      d = p[E + i]; }
    int pos = atomicAdd(&cursor[d], 1);
    eidx[pos] = s;
}

// HS[m,:] = bf16( (X[m,:] @ W) * dinv[m] ).  K=128 always. W kept as packed-bf16 in LDS.
// x_is_ext: 1 -> X dtype follows flags[0]; 0 -> X is internal bf16.
template<int N>
__global__ __launch_bounds__(256) void gemm_k(
    const void* __restrict__ X, const void* __restrict__ W,
    const float* __restrict__ dinv, u16* __restrict__ HS,
    const int* __restrict__ flags, int x_is_ext, int M)
{
    __shared__ u32 wldsu[128 * N / 2];       // packed bf16 pairs
    __shared__ float xlds[16][132];          // +4 pad: kills 4-way bank conflict on column k
    const int t = threadIdx.x;
    const int row0 = blockIdx.x * 16;
    const int f32in = flags[0];

    // stage W (128*N elements), 8 per thread per iter
    for (int i = t * 8; i < 128 * N; i += 2048) {
        u32 pk[4];
        if (f32in) {
            const float* wp = (const float*)W + i;
            #pragma unroll
            for (int j = 0; j < 4; j++)
                pk[j] = ((u32)f2bf(wp[2 * j + 1]) << 16) | (u32)f2bf(wp[2 * j]);
        } else {
            const u32* wp = (const u32*)((const u16*)W + i);
            #pragma unroll
            for (int j = 0; j < 4; j++) pk[j] = wp[j];
        }
        uint4 v; v.x = pk[0]; v.y = pk[1]; v.z = pk[2]; v.w = pk[3];
        *(uint4*)&wldsu[i >> 1] = v;
    }
    // stage 16 X rows (16*128 f32), 8 per thread
    {
        const int r = t >> 4, c = (t & 15) * 8;
        const int grow = row0 + r;
        float xv[8];
        if (grow < M) {
            if (x_is_ext && f32in) {
                const float* xp = (const float*)X + (size_t)grow * 128 + c;
                #pragma unroll
                for (int j = 0; j < 8; j++) xv[j] = xp[j];
            } else {
                const u16* xp = (const u16*)X + (size_t)grow * 128 + c;
                uint4 p = *(const uint4*)xp;
                const u16* sp = (const u16*)&p;
                #pragma unroll
                for (int j = 0; j < 8; j++) xv[j] = bf2f(sp[j]);
            }
        } else {
            #pragma unroll
            for (int j = 0; j < 8; j++) xv[j] = 0.f;
        }
        #pragma unroll
        for (int j = 0; j < 8; j++) xlds[r][c + j] = xv[j];
    }
    __syncthreads();

    constexpr int CPT = N / 16;   // 8 (N=128) / 4 (N=64)
    constexpr int CP2 = CPT / 2;
    const int r = t >> 4;
    const int cb2 = (t & 15) * CP2;          // u32 index within a wlds row
    float acc[CPT];
    #pragma unroll
    for (int c = 0; c < CPT; c++) acc[c] = 0.f;

    #pragma unroll 2
    for (int k = 0; k < 128; k++) {
        float xv = xlds[r][k];
        const u32* wrow = &wldsu[k * (N / 2) + cb2];
        #pragma unroll
        for (int c = 0; c < CP2; c++) {
            u32 w = wrow[c];
            acc[2 * c]     = fmaf(xv, __uint_as_float(w << 16), acc[2 * c]);
            acc[2 * c + 1] = fmaf(xv, __uint_as_float(w & 0xFFFF0000u), acc[2 * c + 1]);
        }
    }

    const int grow = row0 + r;
    if (grow < M) {
        const float dv = dinv[grow];
        u32 pk[CP2];
        #pragma unroll
        for (int c = 0; c < CP2; c++)
            pk[c] = ((u32)f2bf(acc[2 * c + 1] * dv) << 16) | (u32)f2bf(acc[2 * c] * dv);
        u16* op = HS + (size_t)grow * N + cb2 * 2;
        if constexpr (CP2 == 4) {
            uint4 v; v.x = pk[0]; v.y = pk[1]; v.z = pk[2]; v.w = pk[3];
            *(uint4*)op = v;
        } else {
            uint2 v; v.x = pk[0]; v.y = pk[1];
            *(uint2*)op = v;
        }
    }
}

// out[i,:] = act( dinv[i] * (sum_{j in N(i)} hs[j,:] + hs[i,:]) + bias )
// out_is_ext: 1 -> dtype follows flags[0] (final output); 0 -> internal bf16.
template<int N, bool RELU>
__global__ __launch_bounds__(256) void aggregate_k(
    const u16* __restrict__ hs, const int* __restrict__ eidx,
    const int* __restrict__ off, const float* __restrict__ dinv,
    const void* __restrict__ bias, void* __restrict__ out,
    const int* __restrict__ flags, int out_is_ext, int M)
{
    constexpr int TPN = N / 2;               // threads per node, 2 cols each
    constexpr int NPB = 256 / TPN;
    const int node = blockIdx.x * NPB + threadIdx.x / TPN;
    const int lane = threadIdx.x % TPN;
    if (node >= M) return;
    const int f32io = flags[0];
    const int beg = off[node], end = off[node + 1];

    u32 sp = *(const u32*)(hs + (size_t)node * N + lane * 2);  // self-loop term
    float a0 = bf2f((u16)sp), a1 = bf2f((u16)(sp >> 16));
    for (int p = beg; p < end; p++) {
        int s = eidx[p];
        u32 v = *(const u32*)(hs + (size_t)s * N + lane * 2);
        a0 += bf2f((u16)v);
        a1 += bf2f((u16)(v >> 16));
    }
    const float dv = dinv[node];
    float b0, b1;
    if (f32io) { const float* bp = (const float*)bias + lane * 2; b0 = bp[0]; b1 = bp[1]; }
    else {
        u32 bp = *(const u32*)((const u16*)bias + lane * 2);
        b0 = bf2f((u16)bp); b1 = bf2f((u16)(bp >> 16));
    }
    float o0 = fmaf(dv, a0, b0);
    float o1 = fmaf(dv, a1, b1);
    if (RELU) { o0 = fmaxf(o0, 0.f); o1 = fmaxf(o1, 0.f); }
    if (out_is_ext && f32io) {
        float2 v; v.x = o0; v.y = o1;
        *(float2*)((float*)out + (size_t)node * N + lane * 2) = v;
    } else {
        u32 pk = ((u32)f2bf(o1) << 16) | (u32)f2bf(o0);
        *(u32*)((u16*)out + (size_t)node * N + lane * 2) = pk;
    }
}

extern "C" void kernel_launch(void* const* d_in, const int* in_sizes, int n_in,
                              void* d_out, int out_size, void* d_ws, size_t ws_size,
                              hipStream_t stream) {
    const void* x  = d_in[0];
    const void* ei = d_in[1];
    const void* W1 = d_in[2];
    const void* b1 = d_in[3];
    const void* W2 = d_in[4];
    const void* b2 = d_in[5];

    const int M = in_sizes[0] / 128;   // 100000 nodes
    const int E = in_sizes[1] / 2;     // 600000 edges

    char* ws = (char*)d_ws;
    size_t offb = 0;
    auto alloc = [&](size_t bytes) -> void* {
        void* p = ws + offb; offb += (bytes + 255) & ~(size_t)255; return p;
    };
    int*   flags  = (int*)  alloc(256);
    int*   deg    = (int*)  alloc((size_t)M * 4);
    int*   off    = (int*)  alloc((size_t)(M + 1) * 4);
    int*   cursor = (int*)  alloc((size_t)M * 4);
    float* dinv   = (float*)alloc((size_t)M * 4);
    int*   eidx   = (int*)  alloc((size_t)E * 4);
    u16*   hs1    = (u16*)  alloc((size_t)M * 128 * 2);   // 25.6 MB
    u16*   out1   = (u16*)  alloc((size_t)M * 128 * 2);   // 25.6 MB
    u16*   hs2    = hs1;   // layer-2 hs (12.8 MB) reuses hs1 (dead after aggregate1)
    (void)ws_size; (void)n_in; (void)out_size;

    detect_k<<<1, 256, 0, stream>>>((const u32*)x, (const u32*)ei, flags);
    hipMemsetAsync(deg, 0, (size_t)M * 4, stream);
    count_deg_k<<<(E + 255) / 256, 256, 0, stream>>>(ei, E, flags, deg);
    scan_k<<<1, 1024, 0, stream>>>(deg, off, cursor, dinv, M);
    fill_k<<<(E + 255) / 256, 256, 0, stream>>>(ei, E, flags, cursor, eidx);

    // layer 1 (128 -> 128, relu)
    gemm_k<128><<<(M + 15) / 16, 256, 0, stream>>>(x, W1, dinv, hs1, flags, 1, M);
    aggregate_k<128, true><<<(M + 3) / 4, 256, 0, stream>>>(hs1, eidx, off, dinv, b1, out1,
                                                            flags, 0, M);
    // layer 2 (128 -> 64)
    gemm_k<64><<<(M + 15) / 16, 256, 0, stream>>>(out1, W2, dinv, hs2, flags, 0, M);
    aggregate_k<64, false><<<(M + 7) / 8, 256, 0, stream>>>(hs2, eidx, off, dinv, b2, d_out,
                                                            flags, 1, M);
}

// Round 3
// 427.998 us; speedup vs baseline: 1.6249x; 1.6249x over previous
//
#include <hip/hip_runtime.h>
#include <hip/hip_bf16.h>
#include <stdint.h>

typedef unsigned int u32;
typedef unsigned short u16;

#define SCAN_TILE 2048   // elements per block in hierarchical scan (256 thr x 8)

__device__ __forceinline__ float bf2f(u16 u) {
    union { u32 u; float f; } v; v.u = ((u32)u) << 16; return v.f;
}
__device__ __forceinline__ u16 f2bf(float f) {
    u32 u = __float_as_uint(f);
    u32 r = (u + 0x7FFFu + ((u >> 16) & 1u)) >> 16;  // RNE
    return (u16)r;
}

// flags[0] = 1 if external float tensors are f32 (else packed bf16)
// flags[1] = 1 if edge_index is int64 (else int32)
__global__ __launch_bounds__(256) void detect_k(const u32* __restrict__ xw,
                                                const u32* __restrict__ ew,
                                                int* __restrict__ flags) {
    __shared__ int cnt;
    __shared__ u32 orr;
    int t = threadIdx.x;
    if (t == 0) { cnt = 0; orr = 0u; }
    __syncthreads();
    int hits = 0;
    for (int i = t; i < 1024; i += 256) {
        u32 f = (xw[i] >> 7) & 0xFFu;     // bf16-packed: low-half exp field; f32: mantissa bits
        if (f >= 100u && f <= 140u) hits++;
    }
    atomicAdd(&cnt, hits);
    atomicOr(&orr, ew[2 * t + 1]);        // hi-words if int64 (all 0), else edge values
    __syncthreads();
    if (t == 0) {
        flags[0] = (cnt < 512) ? 1 : 0;
        flags[1] = (orr == 0u) ? 1 : 0;
    }
}

__global__ __launch_bounds__(256) void count_deg_k(const void* __restrict__ ei, int E,
                                                   const int* __restrict__ flags,
                                                   int* __restrict__ deg) {
    int i = blockIdx.x * 256 + threadIdx.x;
    if (i >= E) return;
    int d = flags[1] ? (int)((const long long*)ei)[E + i] : ((const int*)ei)[E + i];
    atomicAdd(&deg[d], 1);
}

// ---- hierarchical exclusive scan of deg[0..M) -> off/cursor, plus dinv ----

// pass A: per-block sums of SCAN_TILE-element tiles
__global__ __launch_bounds__(256) void scan_partial_k(const int* __restrict__ deg, int M,
                                                      int* __restrict__ bsum) {
    const int t = threadIdx.x;
    const int base = blockIdx.x * SCAN_TILE + t * 8;
    int s = 0;
    if (base + 8 <= M) {
        int4 a = *(const int4*)(deg + base);
        int4 b = *(const int4*)(deg + base + 4);
        s = a.x + a.y + a.z + a.w + b.x + b.y + b.z + b.w;
    } else {
        for (int j = 0; j < 8; j++) if (base + j < M) s += deg[base + j];
    }
    __shared__ int red[256];
    red[t] = s;
    __syncthreads();
    for (int d = 128; d > 0; d >>= 1) {
        if (t < d) red[t] += red[t + d];
        __syncthreads();
    }
    if (t == 0) bsum[blockIdx.x] = red[0];
}

// pass B: exclusive scan of nb block sums (nb <= 256), in place; off[M] = total
__global__ __launch_bounds__(256) void scan_bsum_k(int* __restrict__ bsum, int nb,
                                                   int* __restrict__ off, int M) {
    __shared__ int buf[2][256];
    const int t = threadIdx.x;
    int v = (t < nb) ? bsum[t] : 0;
    const int own = v;
    buf[0][t] = v;
    __syncthreads();
    int cur = 0;
    for (int d = 1; d < 256; d <<= 1) {
        int x = buf[cur][t];
        if (t >= d) x += buf[cur][t - d];
        buf[cur ^ 1][t] = x;
        __syncthreads();
        cur ^= 1;
    }
    if (t < nb) bsum[t] = buf[cur][t] - own;          // exclusive
    if (t == 255) off[M] = buf[cur][255];             // grand total
}

// pass C: per-block exclusive scan with global base; emit off, cursor, dinv
__global__ __launch_bounds__(256) void scan_final_k(const int* __restrict__ deg,
                                                    const int* __restrict__ bsum, int M,
                                                    int* __restrict__ off,
                                                    int* __restrict__ cursor,
                                                    float* __restrict__ dinv) {
    const int t = threadIdx.x;
    const int base = blockIdx.x * SCAN_TILE + t * 8;
    int v[8];
    int s = 0;
    const bool full = (base + 8 <= M);
    if (full) {
        int4 a = *(const int4*)(deg + base);
        int4 b = *(const int4*)(deg + base + 4);
        v[0] = a.x; v[1] = a.y; v[2] = a.z; v[3] = a.w;
        v[4] = b.x; v[5] = b.y; v[6] = b.z; v[7] = b.w;
        s = v[0] + v[1] + v[2] + v[3] + v[4] + v[5] + v[6] + v[7];
    } else {
        #pragma unroll
        for (int j = 0; j < 8; j++) { v[j] = (base + j < M) ? deg[base + j] : 0; s += v[j]; }
    }
    __shared__ int buf[2][256];
    buf[0][t] = s;
    __syncthreads();
    int cur = 0;
    for (int d = 1; d < 256; d <<= 1) {
        int x = buf[cur][t];
        if (t >= d) x += buf[cur][t - d];
        buf[cur ^ 1][t] = x;
        __syncthreads();
        cur ^= 1;
    }
    int pre = bsum[blockIdx.x] + buf[cur][t] - s;     // global exclusive prefix at base
    int o[8]; float dv[8];
    #pragma unroll
    for (int j = 0; j < 8; j++) {
        o[j] = pre;
        dv[j] = rsqrtf((float)(v[j] + 1));            // +1 self-loop
        pre += v[j];
    }
    if (full) {
        *(int4*)(off + base)     = make_int4(o[0], o[1], o[2], o[3]);
        *(int4*)(off + base + 4) = make_int4(o[4], o[5], o[6], o[7]);
        *(int4*)(cursor + base)     = make_int4(o[0], o[1], o[2], o[3]);
        *(int4*)(cursor + base + 4) = make_int4(o[4], o[5], o[6], o[7]);
        *(float4*)(dinv + base)     = make_float4(dv[0], dv[1], dv[2], dv[3]);
        *(float4*)(dinv + base + 4) = make_float4(dv[4], dv[5], dv[6], dv[7]);
    } else {
        for (int j = 0; j < 8; j++) if (base + j < M) {
            off[base + j] = o[j]; cursor[base + j] = o[j]; dinv[base + j] = dv[j];
        }
    }
}

__global__ __launch_bounds__(256) void fill_k(const void* __restrict__ ei, int E,
                                              const int* __restrict__ flags,
                                              int* __restrict__ cursor, int* __restrict__ eidx) {
    int i = blockIdx.x * 256 + threadIdx.x;
    if (i >= E) return;
    int s, d;
    if (flags[1]) { const long long* p = (const long long*)ei; s = (int)p[i]; d = (int)p[E + i]; }
    else          { const int* p = (const int*)ei;             s = p[i];      d = p[E + i]; }
    int pos = atomicAdd(&cursor[d], 1);
    eidx[pos] = s;
}

// HS[m,:] = bf16( (X[m,:] @ W) * dinv[m] ).  K=128 always. W kept as packed-bf16 in LDS.
// x_is_ext: 1 -> X dtype follows flags[0]; 0 -> X is internal bf16.
template<int N>
__global__ __launch_bounds__(256) void gemm_k(
    const void* __restrict__ X, const void* __restrict__ W,
    const float* __restrict__ dinv, u16* __restrict__ HS,
    const int* __restrict__ flags, int x_is_ext, int M)
{
    __shared__ u32 wldsu[128 * N / 2];       // packed bf16 pairs
    __shared__ float xlds[16][132];          // +4 pad: kills 4-way bank conflict on column k
    const int t = threadIdx.x;
    const int row0 = blockIdx.x * 16;
    const int f32in = flags[0];

    // stage W (128*N elements), 8 per thread per iter
    for (int i = t * 8; i < 128 * N; i += 2048) {
        u32 pk[4];
        if (f32in) {
            const float* wp = (const float*)W + i;
            #pragma unroll
            for (int j = 0; j < 4; j++)
                pk[j] = ((u32)f2bf(wp[2 * j + 1]) << 16) | (u32)f2bf(wp[2 * j]);
        } else {
            const u32* wp = (const u32*)((const u16*)W + i);
            #pragma unroll
            for (int j = 0; j < 4; j++) pk[j] = wp[j];
        }
        uint4 v; v.x = pk[0]; v.y = pk[1]; v.z = pk[2]; v.w = pk[3];
        *(uint4*)&wldsu[i >> 1] = v;
    }
    // stage 16 X rows (16*128 f32), 8 per thread
    {
        const int r = t >> 4, c = (t & 15) * 8;
        const int grow = row0 + r;
        float xv[8];
        if (grow < M) {
            if (x_is_ext && f32in) {
                const float* xp = (const float*)X + (size_t)grow * 128 + c;
                #pragma unroll
                for (int j = 0; j < 8; j++) xv[j] = xp[j];
            } else {
                const u16* xp = (const u16*)X + (size_t)grow * 128 + c;
                uint4 p = *(const uint4*)xp;
                const u16* sp = (const u16*)&p;
                #pragma unroll
                for (int j = 0; j < 8; j++) xv[j] = bf2f(sp[j]);
            }
        } else {
            #pragma unroll
            for (int j = 0; j < 8; j++) xv[j] = 0.f;
        }
        #pragma unroll
        for (int j = 0; j < 8; j++) xlds[r][c + j] = xv[j];
    }
    __syncthreads();

    constexpr int CPT = N / 16;   // 8 (N=128) / 4 (N=64)
    constexpr int CP2 = CPT / 2;
    const int r = t >> 4;
    const int cb2 = (t & 15) * CP2;          // u32 index within a wlds row
    float acc[CPT];
    #pragma unroll
    for (int c = 0; c < CPT; c++) acc[c] = 0.f;

    #pragma unroll 2
    for (int k = 0; k < 128; k++) {
        float xv = xlds[r][k];
        const u32* wrow = &wldsu[k * (N / 2) + cb2];
        #pragma unroll
        for (int c = 0; c < CP2; c++) {
            u32 w = wrow[c];
            acc[2 * c]     = fmaf(xv, __uint_as_float(w << 16), acc[2 * c]);
            acc[2 * c + 1] = fmaf(xv, __uint_as_float(w & 0xFFFF0000u), acc[2 * c + 1]);
        }
    }

    const int grow = row0 + r;
    if (grow < M) {
        const float dv = dinv[grow];
        u32 pk[CP2];
        #pragma unroll
        for (int c = 0; c < CP2; c++)
            pk[c] = ((u32)f2bf(acc[2 * c + 1] * dv) << 16) | (u32)f2bf(acc[2 * c] * dv);
        u16* op = HS + (size_t)grow * N + cb2 * 2;
        if constexpr (CP2 == 4) {
            uint4 v; v.x = pk[0]; v.y = pk[1]; v.z = pk[2]; v.w = pk[3];
            *(uint4*)op = v;
        } else {
            uint2 v; v.x = pk[0]; v.y = pk[1];
            *(uint2*)op = v;
        }
    }
}

// out[i,:] = act( dinv[i] * (sum_{j in N(i)} hs[j,:] + hs[i,:]) + bias )
// out_is_ext: 1 -> dtype follows flags[0] (final output); 0 -> internal bf16.
template<int N, bool RELU>
__global__ __launch_bounds__(256) void aggregate_k(
    const u16* __restrict__ hs, const int* __restrict__ eidx,
    const int* __restrict__ off, const float* __restrict__ dinv,
    const void* __restrict__ bias, void* __restrict__ out,
    const int* __restrict__ flags, int out_is_ext, int M)
{
    constexpr int TPN = N / 2;               // threads per node, 2 cols each
    constexpr int NPB = 256 / TPN;
    const int node = blockIdx.x * NPB + threadIdx.x / TPN;
    const int lane = threadIdx.x % TPN;
    if (node >= M) return;
    const int f32io = flags[0];
    const int beg = off[node], end = off[node + 1];

    u32 sp = *(const u32*)(hs + (size_t)node * N + lane * 2);  // self-loop term
    float a0 = bf2f((u16)sp), a1 = bf2f((u16)(sp >> 16));
    for (int p = beg; p < end; p++) {
        int s = eidx[p];
        u32 v = *(const u32*)(hs + (size_t)s * N + lane * 2);
        a0 += bf2f((u16)v);
        a1 += bf2f((u16)(v >> 16));
    }
    const float dv = dinv[node];
    float b0, b1;
    if (f32io) { const float* bp = (const float*)bias + lane * 2; b0 = bp[0]; b1 = bp[1]; }
    else {
        u32 bp = *(const u32*)((const u16*)bias + lane * 2);
        b0 = bf2f((u16)bp); b1 = bf2f((u16)(bp >> 16));
    }
    float o0 = fmaf(dv, a0, b0);
    float o1 = fmaf(dv, a1, b1);
    if (RELU) { o0 = fmaxf(o0, 0.f); o1 = fmaxf(o1, 0.f); }
    if (out_is_ext && f32io) {
        float2 v; v.x = o0; v.y = o1;
        *(float2*)((float*)out + (size_t)node * N + lane * 2) = v;
    } else {
        u32 pk = ((u32)f2bf(o1) << 16) | (u32)f2bf(o0);
        *(u32*)((u16*)out + (size_t)node * N + lane * 2) = pk;
    }
}

extern "C" void kernel_launch(void* const* d_in, const int* in_sizes, int n_in,
                              void* d_out, int out_size, void* d_ws, size_t ws_size,
                              hipStream_t stream) {
    const void* x  = d_in[0];
    const void* ei = d_in[1];
    const void* W1 = d_in[2];
    const void* b1 = d_in[3];
    const void* W2 = d_in[4];
    const void* b2 = d_in[5];

    const int M = in_sizes[0] / 128;   // 100000 nodes
    const int E = in_sizes[1] / 2;     // 600000 edges
    const int NB = (M + SCAN_TILE - 1) / SCAN_TILE;   // scan blocks (49 for M=100k)

    char* ws = (char*)d_ws;
    size_t offb = 0;
    auto alloc = [&](size_t bytes) -> void* {
        void* p = ws + offb; offb += (bytes + 255) & ~(size_t)255; return p;
    };
    int*   flags  = (int*)  alloc(256);
    int*   bsum   = (int*)  alloc(1024);              // NB <= 256 block sums
    int*   deg    = (int*)  alloc((size_t)M * 4);
    int*   off    = (int*)  alloc((size_t)(M + 1) * 4);
    int*   cursor = (int*)  alloc((size_t)M * 4);
    float* dinv   = (float*)alloc((size_t)M * 4);
    int*   eidx   = (int*)  alloc((size_t)E * 4);
    u16*   hs1    = (u16*)  alloc((size_t)M * 128 * 2);   // 25.6 MB
    u16*   out1   = (u16*)  alloc((size_t)M * 128 * 2);   // 25.6 MB
    u16*   hs2    = hs1;   // layer-2 hs (12.8 MB) reuses hs1 (dead after aggregate1)
    (void)ws_size; (void)n_in; (void)out_size;

    detect_k<<<1, 256, 0, stream>>>((const u32*)x, (const u32*)ei, flags);
    hipMemsetAsync(deg, 0, (size_t)M * 4, stream);
    count_deg_k<<<(E + 255) / 256, 256, 0, stream>>>(ei, E, flags, deg);

    scan_partial_k<<<NB, 256, 0, stream>>>(deg, M, bsum);
    scan_bsum_k<<<1, 256, 0, stream>>>(bsum, NB, off, M);
    scan_final_k<<<NB, 256, 0, stream>>>(deg, bsum, M, off, cursor, dinv);

    fill_k<<<(E + 255) / 256, 256, 0, stream>>>(ei, E, flags, cursor, eidx);

    // layer 1 (128 -> 128, relu)
    gemm_k<128><<<(M + 15) / 16, 256, 0, stream>>>(x, W1, dinv, hs1, flags, 1, M);
    aggregate_k<128, true><<<(M + 3) / 4, 256, 0, stream>>>(hs1, eidx, off, dinv, b1, out1,
                                                            flags, 0, M);
    // layer 2 (128 -> 64)
    gemm_k<64><<<(M + 15) / 16, 256, 0, stream>>>(out1, W2, dinv, hs2, flags, 0, M);
    aggregate_k<64, false><<<(M + 7) / 8, 256, 0, stream>>>(hs2, eidx, off, dinv, b2, d_out,
                                                            flags, 1, M);
}

// Round 4
// 320.701 us; speedup vs baseline: 2.1685x; 1.3346x over previous
//
#include <hip/hip_runtime.h>
#include <hip/hip_bf16.h>
#include <stdint.h>

typedef unsigned int u32;
typedef unsigned short u16;
typedef __attribute__((ext_vector_type(8))) short short8;   // 8 bf16 = 4 VGPRs (MFMA A/B frag)
typedef __attribute__((ext_vector_type(4))) float f32x4;    // MFMA C/D frag

#define SCAN_TILE 2048   // elements per block in hierarchical scan (256 thr x 8)

__device__ __forceinline__ float bf2f(u16 u) {
    union { u32 u; float f; } v; v.u = ((u32)u) << 16; return v.f;
}
__device__ __forceinline__ u16 f2bf(float f) {
    u32 u = __float_as_uint(f);
    u32 r = (u + 0x7FFFu + ((u >> 16) & 1u)) >> 16;  // RNE
    return (u16)r;
}
__device__ __forceinline__ u32 packbf(float lo, float hi) {
    return ((u32)f2bf(hi) << 16) | (u32)f2bf(lo);
}

// flags[0] = 1 if external float tensors are f32 (else packed bf16)
// flags[1] = 1 if edge_index is int64 (else int32)
__global__ __launch_bounds__(256) void detect_k(const u32* __restrict__ xw,
                                                const u32* __restrict__ ew,
                                                int* __restrict__ flags) {
    __shared__ int cnt;
    __shared__ u32 orr;
    int t = threadIdx.x;
    if (t == 0) { cnt = 0; orr = 0u; }
    __syncthreads();
    int hits = 0;
    for (int i = t; i < 1024; i += 256) {
        u32 f = (xw[i] >> 7) & 0xFFu;
        if (f >= 100u && f <= 140u) hits++;
    }
    atomicAdd(&cnt, hits);
    atomicOr(&orr, ew[2 * t + 1]);
    __syncthreads();
    if (t == 0) {
        flags[0] = (cnt < 512) ? 1 : 0;
        flags[1] = (orr == 0u) ? 1 : 0;
    }
}

__global__ __launch_bounds__(256) void count_deg_k(const void* __restrict__ ei, int E,
                                                   const int* __restrict__ flags,
                                                   int* __restrict__ deg) {
    int i = blockIdx.x * 256 + threadIdx.x;
    if (i >= E) return;
    int d = flags[1] ? (int)((const long long*)ei)[E + i] : ((const int*)ei)[E + i];
    atomicAdd(&deg[d], 1);
}

// ---- hierarchical exclusive scan of deg[0..M) -> off/cursor, plus dinv ----
__global__ __launch_bounds__(256) void scan_partial_k(const int* __restrict__ deg, int M,
                                                      int* __restrict__ bsum) {
    const int t = threadIdx.x;
    const int base = blockIdx.x * SCAN_TILE + t * 8;
    int s = 0;
    if (base + 8 <= M) {
        int4 a = *(const int4*)(deg + base);
        int4 b = *(const int4*)(deg + base + 4);
        s = a.x + a.y + a.z + a.w + b.x + b.y + b.z + b.w;
    } else {
        for (int j = 0; j < 8; j++) if (base + j < M) s += deg[base + j];
    }
    __shared__ int red[256];
    red[t] = s;
    __syncthreads();
    for (int d = 128; d > 0; d >>= 1) {
        if (t < d) red[t] += red[t + d];
        __syncthreads();
    }
    if (t == 0) bsum[blockIdx.x] = red[0];
}

__global__ __launch_bounds__(256) void scan_bsum_k(int* __restrict__ bsum, int nb,
                                                   int* __restrict__ off, int M) {
    __shared__ int buf[2][256];
    const int t = threadIdx.x;
    int v = (t < nb) ? bsum[t] : 0;
    const int own = v;
    buf[0][t] = v;
    __syncthreads();
    int cur = 0;
    for (int d = 1; d < 256; d <<= 1) {
        int x = buf[cur][t];
        if (t >= d) x += buf[cur][t - d];
        buf[cur ^ 1][t] = x;
        __syncthreads();
        cur ^= 1;
    }
    if (t < nb) bsum[t] = buf[cur][t] - own;          // exclusive
    if (t == 255) off[M] = buf[cur][255];             // grand total
}

__global__ __launch_bounds__(256) void scan_final_k(const int* __restrict__ deg,
                                                    const int* __restrict__ bsum, int M,
                                                    int* __restrict__ off,
                                                    int* __restrict__ cursor,
                                                    float* __restrict__ dinv) {
    const int t = threadIdx.x;
    const int base = blockIdx.x * SCAN_TILE + t * 8;
    int v[8];
    int s = 0;
    const bool full = (base + 8 <= M);
    if (full) {
        int4 a = *(const int4*)(deg + base);
        int4 b = *(const int4*)(deg + base + 4);
        v[0] = a.x; v[1] = a.y; v[2] = a.z; v[3] = a.w;
        v[4] = b.x; v[5] = b.y; v[6] = b.z; v[7] = b.w;
        s = v[0] + v[1] + v[2] + v[3] + v[4] + v[5] + v[6] + v[7];
    } else {
        #pragma unroll
        for (int j = 0; j < 8; j++) { v[j] = (base + j < M) ? deg[base + j] : 0; s += v[j]; }
    }
    __shared__ int buf[2][256];
    buf[0][t] = s;
    __syncthreads();
    int cur = 0;
    for (int d = 1; d < 256; d <<= 1) {
        int x = buf[cur][t];
        if (t >= d) x += buf[cur][t - d];
        buf[cur ^ 1][t] = x;
        __syncthreads();
        cur ^= 1;
    }
    int pre = bsum[blockIdx.x] + buf[cur][t] - s;
    int o[8]; float dv[8];
    #pragma unroll
    for (int j = 0; j < 8; j++) {
        o[j] = pre;
        dv[j] = rsqrtf((float)(v[j] + 1));            // +1 self-loop
        pre += v[j];
    }
    if (full) {
        *(int4*)(off + base)     = make_int4(o[0], o[1], o[2], o[3]);
        *(int4*)(off + base + 4) = make_int4(o[4], o[5], o[6], o[7]);
        *(int4*)(cursor + base)     = make_int4(o[0], o[1], o[2], o[3]);
        *(int4*)(cursor + base + 4) = make_int4(o[4], o[5], o[6], o[7]);
        *(float4*)(dinv + base)     = make_float4(dv[0], dv[1], dv[2], dv[3]);
        *(float4*)(dinv + base + 4) = make_float4(dv[4], dv[5], dv[6], dv[7]);
    } else {
        for (int j = 0; j < 8; j++) if (base + j < M) {
            off[base + j] = o[j]; cursor[base + j] = o[j]; dinv[base + j] = dv[j];
        }
    }
}

__global__ __launch_bounds__(256) void fill_k(const void* __restrict__ ei, int E,
                                              const int* __restrict__ flags,
                                              int* __restrict__ cursor, int* __restrict__ eidx) {
    int i = blockIdx.x * 256 + threadIdx.x;
    if (i >= E) return;
    int s, d;
    if (flags[1]) { const long long* p = (const long long*)ei; s = (int)p[i]; d = (int)p[E + i]; }
    else          { const int* p = (const int*)ei;             s = p[i];      d = p[E + i]; }
    int pos = atomicAdd(&cursor[d], 1);
    eidx[pos] = s;
}

// ===== MFMA GEMM: HS[m,:] = bf16( (X[m,:] @ W) * dinv[m] ), K=128 =====
// Block = 4 waves; wave w owns rows [row0 + w*32, +32) as 2x 16-row tiles.
// W staged in LDS pre-packed in B-frag order: blds[(kb*N + n)*4 .. +3] = 8 bf16
// of column n, k = kb*8..kb*8+7.  Frags: A[m=lane&15][k=(lane>>4)*8+j],
// B[k=(lane>>4)*8+j][n=lane&15], D: col=lane&15, row=(lane>>4)*4+reg (m89).
template<int N>
__global__ __launch_bounds__(256) void gemm_mfma_k(
    const void* __restrict__ X, const void* __restrict__ W,
    const float* __restrict__ dinv, u16* __restrict__ HS,
    const int* __restrict__ flags, int x_is_ext, int M)
{
    constexpr int NT = N / 16;                 // n-tiles per row-tile
    __shared__ u32 blds[16 * N * 4];           // 16 kb x N cols x 4 u32 (8 bf16)
    const int t = threadIdx.x;
    const int wave = t >> 6, lane = t & 63;
    const int q = lane >> 4, m = lane & 15;
    const int f32w = flags[0];                 // external float dtype
    const bool xf32 = (x_is_ext != 0) && (f32w != 0);
    const int row0 = blockIdx.x * 128 + wave * 32;

    // ---- stage W -> LDS (column-gather; packs 8 consecutive k per chunk) ----
    for (int p = t; p < 16 * N; p += 256) {
        const int n = p & (N - 1);
        const int kb = p / N;
        u32 pk[4];
        if (f32w) {
            const float* wp = (const float*)W + (size_t)(kb * 8) * N + n;
            #pragma unroll
            for (int jj = 0; jj < 4; jj++)
                pk[jj] = packbf(wp[(2 * jj) * N], wp[(2 * jj + 1) * N]);
        } else {
            const u16* wp = (const u16*)W + (size_t)(kb * 8) * N + n;
            #pragma unroll
            for (int jj = 0; jj < 4; jj++)
                pk[jj] = ((u32)wp[(2 * jj + 1) * N] << 16) | (u32)wp[(2 * jj) * N];
        }
        uint4 v; v.x = pk[0]; v.y = pk[1]; v.z = pk[2]; v.w = pk[3];
        *(uint4*)&blds[(size_t)p * 4] = v;
    }

    // ---- load A fragments straight from global (2 row-tiles x 4 k-steps) ----
    u32 a[2][4][4];
    #pragma unroll
    for (int rt = 0; rt < 2; rt++) {
        const int row = row0 + rt * 16 + m;
        const bool ok = row < M;
        if (xf32) {
            const float* xp = (const float*)X + (size_t)row * 128;
            #pragma unroll
            for (int s = 0; s < 4; s++) {
                float4 u = ok ? *(const float4*)(xp + s * 32 + q * 8)
                              : make_float4(0.f, 0.f, 0.f, 0.f);
                float4 v = ok ? *(const float4*)(xp + s * 32 + q * 8 + 4)
                              : make_float4(0.f, 0.f, 0.f, 0.f);
                a[rt][s][0] = packbf(u.x, u.y); a[rt][s][1] = packbf(u.z, u.w);
                a[rt][s][2] = packbf(v.x, v.y); a[rt][s][3] = packbf(v.z, v.w);
            }
        } else {
            const u16* xp = (const u16*)X + (size_t)row * 128;
            #pragma unroll
            for (int s = 0; s < 4; s++) {
                uint4 u = ok ? *(const uint4*)(xp + s * 32 + q * 8)
                             : make_uint4(0u, 0u, 0u, 0u);
                a[rt][s][0] = u.x; a[rt][s][1] = u.y; a[rt][s][2] = u.z; a[rt][s][3] = u.w;
            }
        }
    }
    __syncthreads();

    // ---- MFMA K-loop (fully unrolled: 4 k-steps x NT n-tiles x 2 row-tiles) ----
    f32x4 acc[2][NT];
    #pragma unroll
    for (int rt = 0; rt < 2; rt++)
        #pragma unroll
        for (int tt = 0; tt < NT; tt++)
            acc[rt][tt] = (f32x4){0.f, 0.f, 0.f, 0.f};

    #pragma unroll
    for (int s = 0; s < 4; s++) {
        #pragma unroll
        for (int tt = 0; tt < NT; tt++) {
            union { uint4 u; short8 v; } b;
            b.u = *(const uint4*)&blds[(size_t)(((s * 4 + q) * N + tt * 16 + m)) * 4];
            #pragma unroll
            for (int rt = 0; rt < 2; rt++) {
                union { u32 u[4]; short8 v; } av;
                av.u[0] = a[rt][s][0]; av.u[1] = a[rt][s][1];
                av.u[2] = a[rt][s][2]; av.u[3] = a[rt][s][3];
                acc[rt][tt] = __builtin_amdgcn_mfma_f32_16x16x32_bf16(
                    av.v, b.v, acc[rt][tt], 0, 0, 0);
            }
        }
    }

    // ---- epilogue: dinv scale + bf16 store (D: row=q*4+r, col=tt*16+m) ----
    #pragma unroll
    for (int rt = 0; rt < 2; rt++) {
        float dv[4]; bool ok[4]; int rws[4];
        #pragma unroll
        for (int r = 0; r < 4; r++) {
            rws[r] = row0 + rt * 16 + q * 4 + r;
            ok[r] = rws[r] < M;
            dv[r] = ok[r] ? dinv[rws[r]] : 0.f;
        }
        #pragma unroll
        for (int tt = 0; tt < NT; tt++) {
            #pragma unroll
            for (int r = 0; r < 4; r++) {
                if (ok[r])
                    HS[(size_t)rws[r] * N + tt * 16 + m] = f2bf(acc[rt][tt][r] * dv[r]);
            }
        }
    }
}

// out[i,:] = act( dinv[i] * (sum_{j in N(i)} hs[j,:] + hs[i,:]) + bias )
template<int N, bool RELU>
__global__ __launch_bounds__(256) void aggregate_k(
    const u16* __restrict__ hs, const int* __restrict__ eidx,
    const int* __restrict__ off, const float* __restrict__ dinv,
    const void* __restrict__ bias, void* __restrict__ out,
    const int* __restrict__ flags, int out_is_ext, int M)
{
    constexpr int TPN = N / 2;               // threads per node, 2 cols each
    constexpr int NPB = 256 / TPN;
    const int node = blockIdx.x * NPB + threadIdx.x / TPN;
    const int lane = threadIdx.x % TPN;
    if (node >= M) return;
    const int f32io = flags[0];
    const int beg = off[node], end = off[node + 1];

    u32 sp = *(const u32*)(hs + (size_t)node * N + lane * 2);  // self-loop term
    float a0 = bf2f((u16)sp), a1 = bf2f((u16)(sp >> 16));
    for (int p = beg; p < end; p++) {
        int s = eidx[p];
        u32 v = *(const u32*)(hs + (size_t)s * N + lane * 2);
        a0 += bf2f((u16)v);
        a1 += bf2f((u16)(v >> 16));
    }
    const float dv = dinv[node];
    float b0, b1;
    if (f32io) { const float* bp = (const float*)bias + lane * 2; b0 = bp[0]; b1 = bp[1]; }
    else {
        u32 bp = *(const u32*)((const u16*)bias + lane * 2);
        b0 = bf2f((u16)bp); b1 = bf2f((u16)(bp >> 16));
    }
    float o0 = fmaf(dv, a0, b0);
    float o1 = fmaf(dv, a1, b1);
    if (RELU) { o0 = fmaxf(o0, 0.f); o1 = fmaxf(o1, 0.f); }
    if (out_is_ext && f32io) {
        float2 v; v.x = o0; v.y = o1;
        *(float2*)((float*)out + (size_t)node * N + lane * 2) = v;
    } else {
        u32 pk = ((u32)f2bf(o1) << 16) | (u32)f2bf(o0);
        *(u32*)((u16*)out + (size_t)node * N + lane * 2) = pk;
    }
}

extern "C" void kernel_launch(void* const* d_in, const int* in_sizes, int n_in,
                              void* d_out, int out_size, void* d_ws, size_t ws_size,
                              hipStream_t stream) {
    const void* x  = d_in[0];
    const void* ei = d_in[1];
    const void* W1 = d_in[2];
    const void* b1 = d_in[3];
    const void* W2 = d_in[4];
    const void* b2 = d_in[5];

    const int M = in_sizes[0] / 128;   // 100000 nodes
    const int E = in_sizes[1] / 2;     // 600000 edges
    const int NB = (M + SCAN_TILE - 1) / SCAN_TILE;

    char* ws = (char*)d_ws;
    size_t offb = 0;
    auto alloc = [&](size_t bytes) -> void* {
        void* p = ws + offb; offb += (bytes + 255) & ~(size_t)255; return p;
    };
    int*   flags  = (int*)  alloc(256);
    int*   bsum   = (int*)  alloc(1024);
    int*   deg    = (int*)  alloc((size_t)M * 4);
    int*   off    = (int*)  alloc((size_t)(M + 1) * 4);
    int*   cursor = (int*)  alloc((size_t)M * 4);
    float* dinv   = (float*)alloc((size_t)M * 4);
    int*   eidx   = (int*)  alloc((size_t)E * 4);
    u16*   hs1    = (u16*)  alloc((size_t)M * 128 * 2);   // 25.6 MB
    u16*   out1   = (u16*)  alloc((size_t)M * 128 * 2);   // 25.6 MB
    u16*   hs2    = hs1;   // layer-2 hs reuses hs1 (dead after aggregate1)
    (void)ws_size; (void)n_in; (void)out_size;

    detect_k<<<1, 256, 0, stream>>>((const u32*)x, (const u32*)ei, flags);
    hipMemsetAsync(deg, 0, (size_t)M * 4, stream);
    count_deg_k<<<(E + 255) / 256, 256, 0, stream>>>(ei, E, flags, deg);

    scan_partial_k<<<NB, 256, 0, stream>>>(deg, M, bsum);
    scan_bsum_k<<<1, 256, 0, stream>>>(bsum, NB, off, M);
    scan_final_k<<<NB, 256, 0, stream>>>(deg, bsum, M, off, cursor, dinv);

    fill_k<<<(E + 255) / 256, 256, 0, stream>>>(ei, E, flags, cursor, eidx);

    // layer 1 (128 -> 128, relu)
    gemm_mfma_k<128><<<(M + 127) / 128, 256, 0, stream>>>(x, W1, dinv, hs1, flags, 1, M);
    aggregate_k<128, true><<<(M + 3) / 4, 256, 0, stream>>>(hs1, eidx, off, dinv, b1, out1,
                                                            flags, 0, M);
    // layer 2 (128 -> 64)
    gemm_mfma_k<64><<<(M + 127) / 128, 256, 0, stream>>>(out1, W2, dinv, hs2, flags, 0, M);
    aggregate_k<64, false><<<(M + 7) / 8, 256, 0, stream>>>(hs2, eidx, off, dinv, b2, d_out,
                                                            flags, 1, M);
}

// Round 5
// 259.495 us; speedup vs baseline: 2.6800x; 1.2359x over previous
//
#include <hip/hip_runtime.h>
#include <hip/hip_bf16.h>
#include <stdint.h>

typedef unsigned int u32;
typedef unsigned short u16;
typedef __attribute__((ext_vector_type(8))) short short8;   // 8 bf16 = 4 VGPRs (MFMA A/B frag)
typedef __attribute__((ext_vector_type(4))) float f32x4;    // MFMA C/D frag

#define SCAN_TILE 2048   // elements per block in hierarchical scan (256 thr x 8)

__device__ __forceinline__ float bf2f(u16 u) {
    union { u32 u; float f; } v; v.u = ((u32)u) << 16; return v.f;
}
__device__ __forceinline__ u16 f2bf(float f) {
    u32 u = __float_as_uint(f);
    u32 r = (u + 0x7FFFu + ((u >> 16) & 1u)) >> 16;  // RNE
    return (u16)r;
}
__device__ __forceinline__ u32 packbf(float lo, float hi) {
    return ((u32)f2bf(hi) << 16) | (u32)f2bf(lo);
}

// flags[0] = 1 if external float tensors are f32 (else packed bf16)
// flags[1] = 1 if edge_index is int64 (else int32)
__global__ __launch_bounds__(256) void detect_k(const u32* __restrict__ xw,
                                                const u32* __restrict__ ew,
                                                int* __restrict__ flags) {
    __shared__ int cnt;
    __shared__ u32 orr;
    int t = threadIdx.x;
    if (t == 0) { cnt = 0; orr = 0u; }
    __syncthreads();
    int hits = 0;
    for (int i = t; i < 1024; i += 256) {
        u32 f = (xw[i] >> 7) & 0xFFu;
        if (f >= 100u && f <= 140u) hits++;
    }
    atomicAdd(&cnt, hits);
    atomicOr(&orr, ew[2 * t + 1]);
    __syncthreads();
    if (t == 0) {
        flags[0] = (cnt < 512) ? 1 : 0;
        flags[1] = (orr == 0u) ? 1 : 0;
    }
}

__global__ __launch_bounds__(256) void count_deg_k(const void* __restrict__ ei, int E,
                                                   const int* __restrict__ flags,
                                                   int* __restrict__ deg) {
    int i = blockIdx.x * 256 + threadIdx.x;
    if (i >= E) return;
    int d = flags[1] ? (int)((const long long*)ei)[E + i] : ((const int*)ei)[E + i];
    atomicAdd(&deg[d], 1);
}

// ---- hierarchical exclusive scan of deg[0..M) -> off/cursor, plus dinv ----
__global__ __launch_bounds__(256) void scan_partial_k(const int* __restrict__ deg, int M,
                                                      int* __restrict__ bsum) {
    const int t = threadIdx.x;
    const int base = blockIdx.x * SCAN_TILE + t * 8;
    int s = 0;
    if (base + 8 <= M) {
        int4 a = *(const int4*)(deg + base);
        int4 b = *(const int4*)(deg + base + 4);
        s = a.x + a.y + a.z + a.w + b.x + b.y + b.z + b.w;
    } else {
        for (int j = 0; j < 8; j++) if (base + j < M) s += deg[base + j];
    }
    __shared__ int red[256];
    red[t] = s;
    __syncthreads();
    for (int d = 128; d > 0; d >>= 1) {
        if (t < d) red[t] += red[t + d];
        __syncthreads();
    }
    if (t == 0) bsum[blockIdx.x] = red[0];
}

__global__ __launch_bounds__(256) void scan_bsum_k(int* __restrict__ bsum, int nb,
                                                   int* __restrict__ off, int M) {
    __shared__ int buf[2][256];
    const int t = threadIdx.x;
    int v = (t < nb) ? bsum[t] : 0;
    const int own = v;
    buf[0][t] = v;
    __syncthreads();
    int cur = 0;
    for (int d = 1; d < 256; d <<= 1) {
        int x = buf[cur][t];
        if (t >= d) x += buf[cur][t - d];
        buf[cur ^ 1][t] = x;
        __syncthreads();
        cur ^= 1;
    }
    if (t < nb) bsum[t] = buf[cur][t] - own;          // exclusive
    if (t == 255) off[M] = buf[cur][255];             // grand total
}

__global__ __launch_bounds__(256) void scan_final_k(const int* __restrict__ deg,
                                                    const int* __restrict__ bsum, int M,
                                                    int* __restrict__ off,
                                                    int* __restrict__ cursor,
                                                    float* __restrict__ dinv) {
    const int t = threadIdx.x;
    const int base = blockIdx.x * SCAN_TILE + t * 8;
    int v[8];
    int s = 0;
    const bool full = (base + 8 <= M);
    if (full) {
        int4 a = *(const int4*)(deg + base);
        int4 b = *(const int4*)(deg + base + 4);
        v[0] = a.x; v[1] = a.y; v[2] = a.z; v[3] = a.w;
        v[4] = b.x; v[5] = b.y; v[6] = b.z; v[7] = b.w;
        s = v[0] + v[1] + v[2] + v[3] + v[4] + v[5] + v[6] + v[7];
    } else {
        #pragma unroll
        for (int j = 0; j < 8; j++) { v[j] = (base + j < M) ? deg[base + j] : 0; s += v[j]; }
    }
    __shared__ int buf[2][256];
    buf[0][t] = s;
    __syncthreads();
    int cur = 0;
    for (int d = 1; d < 256; d <<= 1) {
        int x = buf[cur][t];
        if (t >= d) x += buf[cur][t - d];
        buf[cur ^ 1][t] = x;
        __syncthreads();
        cur ^= 1;
    }
    int pre = bsum[blockIdx.x] + buf[cur][t] - s;
    int o[8]; float dv[8];
    #pragma unroll
    for (int j = 0; j < 8; j++) {
        o[j] = pre;
        dv[j] = rsqrtf((float)(v[j] + 1));            // +1 self-loop
        pre += v[j];
    }
    if (full) {
        *(int4*)(off + base)     = make_int4(o[0], o[1], o[2], o[3]);
        *(int4*)(off + base + 4) = make_int4(o[4], o[5], o[6], o[7]);
        *(int4*)(cursor + base)     = make_int4(o[0], o[1], o[2], o[3]);
        *(int4*)(cursor + base + 4) = make_int4(o[4], o[5], o[6], o[7]);
        *(float4*)(dinv + base)     = make_float4(dv[0], dv[1], dv[2], dv[3]);
        *(float4*)(dinv + base + 4) = make_float4(dv[4], dv[5], dv[6], dv[7]);
    } else {
        for (int j = 0; j < 8; j++) if (base + j < M) {
            off[base + j] = o[j]; cursor[base + j] = o[j]; dinv[base + j] = dv[j];
        }
    }
}

__global__ __launch_bounds__(256) void fill_k(const void* __restrict__ ei, int E,
                                              const int* __restrict__ flags,
                                              int* __restrict__ cursor, int* __restrict__ eidx) {
    int i = blockIdx.x * 256 + threadIdx.x;
    if (i >= E) return;
    int s, d;
    if (flags[1]) { const long long* p = (const long long*)ei; s = (int)p[i]; d = (int)p[E + i]; }
    else          { const int* p = (const int*)ei;             s = p[i];      d = p[E + i]; }
    int pos = atomicAdd(&cursor[d], 1);
    eidx[pos] = s;
}

// ===== MFMA GEMM: HS[m,:] = bf16( (X[m,:] @ W) * dinv[m] ), K=128 =====
template<int N>
__global__ __launch_bounds__(256) void gemm_mfma_k(
    const void* __restrict__ X, const void* __restrict__ W,
    const float* __restrict__ dinv, u16* __restrict__ HS,
    const int* __restrict__ flags, int x_is_ext, int M)
{
    constexpr int NT = N / 16;                 // n-tiles per row-tile
    __shared__ u32 blds[16 * N * 4];           // 16 kb x N cols x 4 u32 (8 bf16)
    const int t = threadIdx.x;
    const int wave = t >> 6, lane = t & 63;
    const int q = lane >> 4, m = lane & 15;
    const int f32w = flags[0];                 // external float dtype
    const bool xf32 = (x_is_ext != 0) && (f32w != 0);
    const int row0 = blockIdx.x * 128 + wave * 32;

    // ---- stage W -> LDS (B-frag order: 8 consecutive k per 16B chunk) ----
    for (int p = t; p < 16 * N; p += 256) {
        const int n = p & (N - 1);
        const int kb = p / N;
        u32 pk[4];
        if (f32w) {
            const float* wp = (const float*)W + (size_t)(kb * 8) * N + n;
            #pragma unroll
            for (int jj = 0; jj < 4; jj++)
                pk[jj] = packbf(wp[(2 * jj) * N], wp[(2 * jj + 1) * N]);
        } else {
            const u16* wp = (const u16*)W + (size_t)(kb * 8) * N + n;
            #pragma unroll
            for (int jj = 0; jj < 4; jj++)
                pk[jj] = ((u32)wp[(2 * jj + 1) * N] << 16) | (u32)wp[(2 * jj) * N];
        }
        uint4 v; v.x = pk[0]; v.y = pk[1]; v.z = pk[2]; v.w = pk[3];
        *(uint4*)&blds[(size_t)p * 4] = v;
    }

    // ---- load A fragments straight from global (2 row-tiles x 4 k-steps) ----
    u32 a[2][4][4];
    #pragma unroll
    for (int rt = 0; rt < 2; rt++) {
        const int row = row0 + rt * 16 + m;
        const bool ok = row < M;
        if (xf32) {
            const float* xp = (const float*)X + (size_t)row * 128;
            #pragma unroll
            for (int s = 0; s < 4; s++) {
                float4 u = ok ? *(const float4*)(xp + s * 32 + q * 8)
                              : make_float4(0.f, 0.f, 0.f, 0.f);
                float4 v = ok ? *(const float4*)(xp + s * 32 + q * 8 + 4)
                              : make_float4(0.f, 0.f, 0.f, 0.f);
                a[rt][s][0] = packbf(u.x, u.y); a[rt][s][1] = packbf(u.z, u.w);
                a[rt][s][2] = packbf(v.x, v.y); a[rt][s][3] = packbf(v.z, v.w);
            }
        } else {
            const u16* xp = (const u16*)X + (size_t)row * 128;
            #pragma unroll
            for (int s = 0; s < 4; s++) {
                uint4 u = ok ? *(const uint4*)(xp + s * 32 + q * 8)
                             : make_uint4(0u, 0u, 0u, 0u);
                a[rt][s][0] = u.x; a[rt][s][1] = u.y; a[rt][s][2] = u.z; a[rt][s][3] = u.w;
            }
        }
    }
    __syncthreads();

    // ---- MFMA K-loop ----
    f32x4 acc[2][NT];
    #pragma unroll
    for (int rt = 0; rt < 2; rt++)
        #pragma unroll
        for (int tt = 0; tt < NT; tt++)
            acc[rt][tt] = (f32x4){0.f, 0.f, 0.f, 0.f};

    #pragma unroll
    for (int s = 0; s < 4; s++) {
        #pragma unroll
        for (int tt = 0; tt < NT; tt++) {
            union { uint4 u; short8 v; } b;
            b.u = *(const uint4*)&blds[(size_t)(((s * 4 + q) * N + tt * 16 + m)) * 4];
            #pragma unroll
            for (int rt = 0; rt < 2; rt++) {
                union { u32 u[4]; short8 v; } av;
                av.u[0] = a[rt][s][0]; av.u[1] = a[rt][s][1];
                av.u[2] = a[rt][s][2]; av.u[3] = a[rt][s][3];
                acc[rt][tt] = __builtin_amdgcn_mfma_f32_16x16x32_bf16(
                    av.v, b.v, acc[rt][tt], 0, 0, 0);
            }
        }
    }

    // ---- epilogue: dinv scale + bf16 store (D: row=q*4+r, col=tt*16+m) ----
    #pragma unroll
    for (int rt = 0; rt < 2; rt++) {
        float dv[4]; bool ok[4]; int rws[4];
        #pragma unroll
        for (int r = 0; r < 4; r++) {
            rws[r] = row0 + rt * 16 + q * 4 + r;
            ok[r] = rws[r] < M;
            dv[r] = ok[r] ? dinv[rws[r]] : 0.f;
        }
        #pragma unroll
        for (int tt = 0; tt < NT; tt++) {
            #pragma unroll
            for (int r = 0; r < 4; r++) {
                if (ok[r])
                    HS[(size_t)rws[r] * N + tt * 16 + m] = f2bf(acc[rt][tt][r] * dv[r]);
            }
        }
    }
}

// out[i,:] = act( dinv[i] * (sum_{j in N(i)} hs[j,:] + hs[i,:]) + bias )
// v2: TPN = N/8 lanes/node, 16B gathers, 4-edge unroll for MLP.
template<int N, bool RELU>
__global__ __launch_bounds__(256) void aggregate_k(
    const u16* __restrict__ hs, const int* __restrict__ eidx,
    const int* __restrict__ off, const float* __restrict__ dinv,
    const void* __restrict__ bias, void* __restrict__ out,
    const int* __restrict__ flags, int out_is_ext, int M)
{
    constexpr int TPN = N / 8;               // threads per node, 8 cols each
    constexpr int NPB = 256 / TPN;
    const int node = blockIdx.x * NPB + threadIdx.x / TPN;
    const int lane = threadIdx.x % TPN;
    if (node >= M) return;
    const int f32io = flags[0];
    const int beg = off[node], end = off[node + 1];
    const int c8 = lane * 8;
    const u16* __restrict__ hrow = hs + c8;

    float a[8];
    {
        uint4 sp = *(const uint4*)(hrow + (size_t)node * N);   // self-loop term
        const u16* s = (const u16*)&sp;
        #pragma unroll
        for (int j = 0; j < 8; j++) a[j] = bf2f(s[j]);
    }

    int p = beg;
    for (; p + 4 <= end; p += 4) {
        const int s0 = eidx[p + 0], s1 = eidx[p + 1];
        const int s2 = eidx[p + 2], s3 = eidx[p + 3];
        uint4 v0 = *(const uint4*)(hrow + (size_t)s0 * N);
        uint4 v1 = *(const uint4*)(hrow + (size_t)s1 * N);
        uint4 v2 = *(const uint4*)(hrow + (size_t)s2 * N);
        uint4 v3 = *(const uint4*)(hrow + (size_t)s3 * N);
        const u16* q0 = (const u16*)&v0; const u16* q1 = (const u16*)&v1;
        const u16* q2 = (const u16*)&v2; const u16* q3 = (const u16*)&v3;
        #pragma unroll
        for (int j = 0; j < 8; j++)
            a[j] += (bf2f(q0[j]) + bf2f(q1[j])) + (bf2f(q2[j]) + bf2f(q3[j]));
    }
    for (; p < end; p++) {
        const int s = eidx[p];
        uint4 v = *(const uint4*)(hrow + (size_t)s * N);
        const u16* q = (const u16*)&v;
        #pragma unroll
        for (int j = 0; j < 8; j++) a[j] += bf2f(q[j]);
    }

    const float dv = dinv[node];
    float b[8];
    if (f32io) {
        float4 u = *(const float4*)((const float*)bias + c8);
        float4 v = *(const float4*)((const float*)bias + c8 + 4);
        b[0] = u.x; b[1] = u.y; b[2] = u.z; b[3] = u.w;
        b[4] = v.x; b[5] = v.y; b[6] = v.z; b[7] = v.w;
    } else {
        uint4 u = *(const uint4*)((const u16*)bias + c8);
        const u16* s = (const u16*)&u;
        #pragma unroll
        for (int j = 0; j < 8; j++) b[j] = bf2f(s[j]);
    }
    float o[8];
    #pragma unroll
    for (int j = 0; j < 8; j++) {
        o[j] = fmaf(dv, a[j], b[j]);
        if (RELU) o[j] = fmaxf(o[j], 0.f);
    }
    if (out_is_ext && f32io) {
        float* op = (float*)out + (size_t)node * N + c8;
        *(float4*)op       = make_float4(o[0], o[1], o[2], o[3]);
        *(float4*)(op + 4) = make_float4(o[4], o[5], o[6], o[7]);
    } else {
        uint4 pk;
        pk.x = packbf(o[0], o[1]); pk.y = packbf(o[2], o[3]);
        pk.z = packbf(o[4], o[5]); pk.w = packbf(o[6], o[7]);
        *(uint4*)((u16*)out + (size_t)node * N + c8) = pk;
    }
}

extern "C" void kernel_launch(void* const* d_in, const int* in_sizes, int n_in,
                              void* d_out, int out_size, void* d_ws, size_t ws_size,
                              hipStream_t stream) {
    const void* x  = d_in[0];
    const void* ei = d_in[1];
    const void* W1 = d_in[2];
    const void* b1 = d_in[3];
    const void* W2 = d_in[4];
    const void* b2 = d_in[5];

    const int M = in_sizes[0] / 128;   // 100000 nodes
    const int E = in_sizes[1] / 2;     // 600000 edges
    const int NB = (M + SCAN_TILE - 1) / SCAN_TILE;

    char* ws = (char*)d_ws;
    size_t offb = 0;
    auto alloc = [&](size_t bytes) -> void* {
        void* p = ws + offb; offb += (bytes + 255) & ~(size_t)255; return p;
    };
    int*   flags  = (int*)  alloc(256);
    int*   bsum   = (int*)  alloc(1024);
    int*   deg    = (int*)  alloc((size_t)M * 4);
    int*   off    = (int*)  alloc((size_t)(M + 1) * 4);
    int*   cursor = (int*)  alloc((size_t)M * 4);
    float* dinv   = (float*)alloc((size_t)M * 4);
    int*   eidx   = (int*)  alloc((size_t)E * 4);
    u16*   hs1    = (u16*)  alloc((size_t)M * 128 * 2);   // 25.6 MB
    u16*   out1   = (u16*)  alloc((size_t)M * 128 * 2);   // 25.6 MB
    u16*   hs2    = hs1;   // layer-2 hs reuses hs1 (dead after aggregate1)
    (void)ws_size; (void)n_in; (void)out_size;

    detect_k<<<1, 256, 0, stream>>>((const u32*)x, (const u32*)ei, flags);
    hipMemsetAsync(deg, 0, (size_t)M * 4, stream);
    count_deg_k<<<(E + 255) / 256, 256, 0, stream>>>(ei, E, flags, deg);

    scan_partial_k<<<NB, 256, 0, stream>>>(deg, M, bsum);
    scan_bsum_k<<<1, 256, 0, stream>>>(bsum, NB, off, M);
    scan_final_k<<<NB, 256, 0, stream>>>(deg, bsum, M, off, cursor, dinv);

    fill_k<<<(E + 255) / 256, 256, 0, stream>>>(ei, E, flags, cursor, eidx);

    // layer 1 (128 -> 128, relu): aggregate NPB = 256/(128/8) = 16 nodes/block
    gemm_mfma_k<128><<<(M + 127) / 128, 256, 0, stream>>>(x, W1, dinv, hs1, flags, 1, M);
    aggregate_k<128, true><<<(M + 15) / 16, 256, 0, stream>>>(hs1, eidx, off, dinv, b1, out1,
                                                              flags, 0, M);
    // layer 2 (128 -> 64): aggregate NPB = 256/(64/8) = 32 nodes/block
    gemm_mfma_k<64><<<(M + 127) / 128, 256, 0, stream>>>(out1, W2, dinv, hs2, flags, 0, M);
    aggregate_k<64, false><<<(M + 31) / 32, 256, 0, stream>>>(hs2, eidx, off, dinv, b2, d_out,
                                                              flags, 1, M);
}

// Round 6
// 248.263 us; speedup vs baseline: 2.8012x; 1.0452x over previous
//
#include <hip/hip_runtime.h>
#include <hip/hip_bf16.h>
#include <stdint.h>

typedef unsigned int u32;
typedef unsigned short u16;
typedef __attribute__((ext_vector_type(8))) short short8;   // 8 bf16 = 4 VGPRs (MFMA A/B frag)
typedef __attribute__((ext_vector_type(4))) float f32x4;    // MFMA C/D frag

#define SCAN_TILE 2048   // elements per block in hierarchical scan (256 thr x 8)

__device__ __forceinline__ float bf2f(u16 u) {
    union { u32 u; float f; } v; v.u = ((u32)u) << 16; return v.f;
}
__device__ __forceinline__ u16 f2bf(float f) {
    u32 u = __float_as_uint(f);
    u32 r = (u + 0x7FFFu + ((u >> 16) & 1u)) >> 16;  // RNE
    return (u16)r;
}
__device__ __forceinline__ u32 packbf(float lo, float hi) {
    return ((u32)f2bf(hi) << 16) | (u32)f2bf(lo);
}

// flags[0] = 1 if external float tensors are f32 (else packed bf16)
// flags[1] = 1 if edge_index is int64 (else int32)
__global__ __launch_bounds__(256) void detect_k(const u32* __restrict__ xw,
                                                const u32* __restrict__ ew,
                                                int* __restrict__ flags) {
    __shared__ int cnt;
    __shared__ u32 orr;
    int t = threadIdx.x;
    if (t == 0) { cnt = 0; orr = 0u; }
    __syncthreads();
    int hits = 0;
    for (int i = t; i < 1024; i += 256) {
        u32 f = (xw[i] >> 7) & 0xFFu;
        if (f >= 100u && f <= 140u) hits++;
    }
    atomicAdd(&cnt, hits);
    atomicOr(&orr, ew[2 * t + 1]);
    __syncthreads();
    if (t == 0) {
        flags[0] = (cnt < 512) ? 1 : 0;
        flags[1] = (orr == 0u) ? 1 : 0;
    }
}

// Pre-pack W into B-fragment order, ONCE per launch: chunk p = kb*N+n holds
// 8 bf16 of column n, rows k = kb*8..kb*8+7.
template<int N>
__global__ __launch_bounds__(256) void w_pack_k(const void* __restrict__ W,
                                                uint4* __restrict__ wpk,
                                                const int* __restrict__ flags) {
    const int p = blockIdx.x * 256 + threadIdx.x;
    if (p >= 16 * N) return;
    const int n = p & (N - 1);
    const int kb = p >> ((N == 128) ? 7 : 6);
    u32 pk[4];
    if (flags[0]) {
        const float* wp = (const float*)W + (size_t)(kb * 8) * N + n;
        #pragma unroll
        for (int jj = 0; jj < 4; jj++)
            pk[jj] = packbf(wp[(2 * jj) * N], wp[(2 * jj + 1) * N]);
    } else {
        const u16* wp = (const u16*)W + (size_t)(kb * 8) * N + n;
        #pragma unroll
        for (int jj = 0; jj < 4; jj++)
            pk[jj] = ((u32)wp[(2 * jj + 1) * N] << 16) | (u32)wp[(2 * jj) * N];
    }
    uint4 v; v.x = pk[0]; v.y = pk[1]; v.z = pk[2]; v.w = pk[3];
    wpk[p] = v;
}

__global__ __launch_bounds__(256) void count_deg_k(const void* __restrict__ ei, int E,
                                                   const int* __restrict__ flags,
                                                   int* __restrict__ deg) {
    int i = blockIdx.x * 256 + threadIdx.x;
    if (i >= E) return;
    int d = flags[1] ? (int)((const long long*)ei)[E + i] : ((const int*)ei)[E + i];
    atomicAdd(&deg[d], 1);
}

// ---- hierarchical exclusive scan of deg[0..M) -> off/cursor, plus dinv ----
__global__ __launch_bounds__(256) void scan_partial_k(const int* __restrict__ deg, int M,
                                                      int* __restrict__ bsum) {
    const int t = threadIdx.x;
    const int base = blockIdx.x * SCAN_TILE + t * 8;
    int s = 0;
    if (base + 8 <= M) {
        int4 a = *(const int4*)(deg + base);
        int4 b = *(const int4*)(deg + base + 4);
        s = a.x + a.y + a.z + a.w + b.x + b.y + b.z + b.w;
    } else {
        for (int j = 0; j < 8; j++) if (base + j < M) s += deg[base + j];
    }
    __shared__ int red[256];
    red[t] = s;
    __syncthreads();
    for (int d = 128; d > 0; d >>= 1) {
        if (t < d) red[t] += red[t + d];
        __syncthreads();
    }
    if (t == 0) bsum[blockIdx.x] = red[0];
}

__global__ __launch_bounds__(256) void scan_bsum_k(int* __restrict__ bsum, int nb,
                                                   int* __restrict__ off, int M) {
    __shared__ int buf[2][256];
    const int t = threadIdx.x;
    int v = (t < nb) ? bsum[t] : 0;
    const int own = v;
    buf[0][t] = v;
    __syncthreads();
    int cur = 0;
    for (int d = 1; d < 256; d <<= 1) {
        int x = buf[cur][t];
        if (t >= d) x += buf[cur][t - d];
        buf[cur ^ 1][t] = x;
        __syncthreads();
        cur ^= 1;
    }
    if (t < nb) bsum[t] = buf[cur][t] - own;          // exclusive
    if (t == 255) off[M] = buf[cur][255];             // grand total
}

__global__ __launch_bounds__(256) void scan_final_k(const int* __restrict__ deg,
                                                    const int* __restrict__ bsum, int M,
                                                    int* __restrict__ off,
                                                    int* __restrict__ cursor,
                                                    float* __restrict__ dinv) {
    const int t = threadIdx.x;
    const int base = blockIdx.x * SCAN_TILE + t * 8;
    int v[8];
    int s = 0;
    const bool full = (base + 8 <= M);
    if (full) {
        int4 a = *(const int4*)(deg + base);
        int4 b = *(const int4*)(deg + base + 4);
        v[0] = a.x; v[1] = a.y; v[2] = a.z; v[3] = a.w;
        v[4] = b.x; v[5] = b.y; v[6] = b.z; v[7] = b.w;
        s = v[0] + v[1] + v[2] + v[3] + v[4] + v[5] + v[6] + v[7];
    } else {
        #pragma unroll
        for (int j = 0; j < 8; j++) { v[j] = (base + j < M) ? deg[base + j] : 0; s += v[j]; }
    }
    __shared__ int buf[2][256];
    buf[0][t] = s;
    __syncthreads();
    int cur = 0;
    for (int d = 1; d < 256; d <<= 1) {
        int x = buf[cur][t];
        if (t >= d) x += buf[cur][t - d];
        buf[cur ^ 1][t] = x;
        __syncthreads();
        cur ^= 1;
    }
    int pre = bsum[blockIdx.x] + buf[cur][t] - s;
    int o[8]; float dv[8];
    #pragma unroll
    for (int j = 0; j < 8; j++) {
        o[j] = pre;
        dv[j] = rsqrtf((float)(v[j] + 1));            // +1 self-loop
        pre += v[j];
    }
    if (full) {
        *(int4*)(off + base)     = make_int4(o[0], o[1], o[2], o[3]);
        *(int4*)(off + base + 4) = make_int4(o[4], o[5], o[6], o[7]);
        *(int4*)(cursor + base)     = make_int4(o[0], o[1], o[2], o[3]);
        *(int4*)(cursor + base + 4) = make_int4(o[4], o[5], o[6], o[7]);
        *(float4*)(dinv + base)     = make_float4(dv[0], dv[1], dv[2], dv[3]);
        *(float4*)(dinv + base + 4) = make_float4(dv[4], dv[5], dv[6], dv[7]);
    } else {
        for (int j = 0; j < 8; j++) if (base + j < M) {
            off[base + j] = o[j]; cursor[base + j] = o[j]; dinv[base + j] = dv[j];
        }
    }
}

__global__ __launch_bounds__(256) void fill_k(const void* __restrict__ ei, int E,
                                              const int* __restrict__ flags,
                                              int* __restrict__ cursor, int* __restrict__ eidx) {
    int i = blockIdx.x * 256 + threadIdx.x;
    if (i >= E) return;
    int s, d;
    if (flags[1]) { const long long* p = (const long long*)ei; s = (int)p[i]; d = (int)p[E + i]; }
    else          { const int* p = (const int*)ei;             s = p[i];      d = p[E + i]; }
    int pos = atomicAdd(&cursor[d], 1);
    eidx[pos] = s;
}

// ===== MFMA GEMM v2: HS[m,:] = bf16( (X[m,:] @ W) * dinv[m] ), K=128 =====
// Block = 256 thr / 4 waves, 128 rows. X tile staged to LDS via coalesced
// loads; A-frags via ds_read_b128; B-frags direct from pre-packed global wpk
// (L2-resident, 256B-segment loads); epilogue repacked through wave-private
// LDS (reusing xlds rows — no barrier needed) into 16B coalesced stores.
template<int N>
__global__ __launch_bounds__(256) void gemm_mfma_k(
    const void* __restrict__ X, const uint4* __restrict__ wpk,
    const float* __restrict__ dinv, u16* __restrict__ HS,
    const int* __restrict__ flags, int x_is_ext, int M)
{
    constexpr int NT = N / 16;                  // n-tiles
    constexpr int NC8 = N / 8;                  // 16B chunks per output row
    __shared__ u32 xlds[128 * 64];              // 128 rows x 256B bf16 (32 KB)
    const int t = threadIdx.x;
    const int wave = t >> 6, lane = t & 63;
    const int q = lane >> 4, m = lane & 15;
    const bool xf32 = (x_is_ext != 0) && (flags[0] != 0);
    const int row0 = blockIdx.x * 128;

    // ---- stage X tile -> LDS (coalesced; 2048 chunks of 16B bf16) ----
    for (int c = t; c < 2048; c += 256) {
        const int row = c >> 4, c8 = c & 15;
        const int grow = row0 + row;
        uint4 pk = make_uint4(0u, 0u, 0u, 0u);
        if (grow < M) {
            if (xf32) {
                const float* xp = (const float*)X + (size_t)grow * 128 + c8 * 8;
                float4 u = *(const float4*)xp;
                float4 v = *(const float4*)(xp + 4);
                pk.x = packbf(u.x, u.y); pk.y = packbf(u.z, u.w);
                pk.z = packbf(v.x, v.y); pk.w = packbf(v.z, v.w);
            } else {
                pk = *(const uint4*)((const u16*)X + (size_t)grow * 128 + c8 * 8);
            }
        }
        *(uint4*)&xlds[row * 64 + c8 * 4] = pk;
    }
    __syncthreads();

    // ---- A-fragments from LDS (wave's own 32 rows) ----
    union { uint4 u; short8 v; } a[2][4];
    #pragma unroll
    for (int rt = 0; rt < 2; rt++)
        #pragma unroll
        for (int s = 0; s < 4; s++)
            a[rt][s].u = *(const uint4*)&xlds[(wave * 32 + rt * 16 + m) * 64 + (s * 4 + q) * 4];

    // ---- MFMA loop; B-frags direct from global wpk ----
    f32x4 acc[2][NT];
    #pragma unroll
    for (int rt = 0; rt < 2; rt++)
        #pragma unroll
        for (int tt = 0; tt < NT; tt++)
            acc[rt][tt] = (f32x4){0.f, 0.f, 0.f, 0.f};

    #pragma unroll
    for (int s = 0; s < 4; s++) {
        union { uint4 u; short8 v; } b[NT];
        #pragma unroll
        for (int tt = 0; tt < NT; tt++)
            b[tt].u = wpk[(s * 4 + q) * N + tt * 16 + m];
        #pragma unroll
        for (int tt = 0; tt < NT; tt++)
            #pragma unroll
            for (int rt = 0; rt < 2; rt++)
                acc[rt][tt] = __builtin_amdgcn_mfma_f32_16x16x32_bf16(
                    a[rt][s].v, b[tt].v, acc[rt][tt], 0, 0, 0);
    }

    // ---- epilogue: dinv scale, repack via wave-private LDS, 16B stores ----
    float dv[2][4];
    #pragma unroll
    for (int rt = 0; rt < 2; rt++)
        #pragma unroll
        for (int r = 0; r < 4; r++) {
            const int grow = row0 + wave * 32 + rt * 16 + q * 4 + r;
            dv[rt][r] = (grow < M) ? dinv[grow] : 0.f;
        }

    u16* orow = (u16*)&xlds[wave * 32 * 64];    // wave-private 8KB region
    #pragma unroll
    for (int rt = 0; rt < 2; rt++)
        #pragma unroll
        for (int tt = 0; tt < NT; tt++)
            #pragma unroll
            for (int r = 0; r < 4; r++)
                orow[(rt * 16 + q * 4 + r) * N + tt * 16 + m] =
                    f2bf(acc[rt][tt][r] * dv[rt][r]);

    constexpr int ITER = 16 * NC8 / 64;         // 4 (N=128) / 2 (N=64)
    #pragma unroll
    for (int rt = 0; rt < 2; rt++) {
        #pragma unroll
        for (int j = 0; j < ITER; j++) {
            const int cc = lane + j * 64;
            const int lrow = cc / NC8, c8 = cc % NC8;
            const int grow = row0 + wave * 32 + rt * 16 + lrow;
            uint4 v = *(const uint4*)&((const u32*)orow)[(rt * 16 + lrow) * (N / 2) + c8 * 4];
            if (grow < M)
                *(uint4*)(HS + (size_t)grow * N + c8 * 8) = v;
        }
    }
}

// out[i,:] = act( dinv[i] * (sum_{j in N(i)} hs[j,:] + hs[i,:]) + bias )
// TPN = N/8 lanes/node, 16B gathers, 4-edge unroll for MLP.
template<int N, bool RELU>
__global__ __launch_bounds__(256) void aggregate_k(
    const u16* __restrict__ hs, const int* __restrict__ eidx,
    const int* __restrict__ off, const float* __restrict__ dinv,
    const void* __restrict__ bias, void* __restrict__ out,
    const int* __restrict__ flags, int out_is_ext, int M)
{
    constexpr int TPN = N / 8;               // threads per node, 8 cols each
    constexpr int NPB = 256 / TPN;
    const int node = blockIdx.x * NPB + threadIdx.x / TPN;
    const int lane = threadIdx.x % TPN;
    if (node >= M) return;
    const int f32io = flags[0];
    const int beg = off[node], end = off[node + 1];
    const int c8 = lane * 8;
    const u16* __restrict__ hrow = hs + c8;

    float a[8];
    {
        uint4 sp = *(const uint4*)(hrow + (size_t)node * N);   // self-loop term
        const u16* s = (const u16*)&sp;
        #pragma unroll
        for (int j = 0; j < 8; j++) a[j] = bf2f(s[j]);
    }

    int p = beg;
    for (; p + 4 <= end; p += 4) {
        const int s0 = eidx[p + 0], s1 = eidx[p + 1];
        const int s2 = eidx[p + 2], s3 = eidx[p + 3];
        uint4 v0 = *(const uint4*)(hrow + (size_t)s0 * N);
        uint4 v1 = *(const uint4*)(hrow + (size_t)s1 * N);
        uint4 v2 = *(const uint4*)(hrow + (size_t)s2 * N);
        uint4 v3 = *(const uint4*)(hrow + (size_t)s3 * N);
        const u16* q0 = (const u16*)&v0; const u16* q1 = (const u16*)&v1;
        const u16* q2 = (const u16*)&v2; const u16* q3 = (const u16*)&v3;
        #pragma unroll
        for (int j = 0; j < 8; j++)
            a[j] += (bf2f(q0[j]) + bf2f(q1[j])) + (bf2f(q2[j]) + bf2f(q3[j]));
    }
    for (; p < end; p++) {
        const int s = eidx[p];
        uint4 v = *(const uint4*)(hrow + (size_t)s * N);
        const u16* q = (const u16*)&v;
        #pragma unroll
        for (int j = 0; j < 8; j++) a[j] += bf2f(q[j]);
    }

    const float dv = dinv[node];
    float b[8];
    if (f32io) {
        float4 u = *(const float4*)((const float*)bias + c8);
        float4 v = *(const float4*)((const float*)bias + c8 + 4);
        b[0] = u.x; b[1] = u.y; b[2] = u.z; b[3] = u.w;
        b[4] = v.x; b[5] = v.y; b[6] = v.z; b[7] = v.w;
    } else {
        uint4 u = *(const uint4*)((const u16*)bias + c8);
        const u16* s = (const u16*)&u;
        #pragma unroll
        for (int j = 0; j < 8; j++) b[j] = bf2f(s[j]);
    }
    float o[8];
    #pragma unroll
    for (int j = 0; j < 8; j++) {
        o[j] = fmaf(dv, a[j], b[j]);
        if (RELU) o[j] = fmaxf(o[j], 0.f);
    }
    if (out_is_ext && f32io) {
        float* op = (float*)out + (size_t)node * N + c8;
        *(float4*)op       = make_float4(o[0], o[1], o[2], o[3]);
        *(float4*)(op + 4) = make_float4(o[4], o[5], o[6], o[7]);
    } else {
        uint4 pk;
        pk.x = packbf(o[0], o[1]); pk.y = packbf(o[2], o[3]);
        pk.z = packbf(o[4], o[5]); pk.w = packbf(o[6], o[7]);
        *(uint4*)((u16*)out + (size_t)node * N + c8) = pk;
    }
}

extern "C" void kernel_launch(void* const* d_in, const int* in_sizes, int n_in,
                              void* d_out, int out_size, void* d_ws, size_t ws_size,
                              hipStream_t stream) {
    const void* x  = d_in[0];
    const void* ei = d_in[1];
    const void* W1 = d_in[2];
    const void* b1 = d_in[3];
    const void* W2 = d_in[4];
    const void* b2 = d_in[5];

    const int M = in_sizes[0] / 128;   // 100000 nodes
    const int E = in_sizes[1] / 2;     // 600000 edges
    const int NB = (M + SCAN_TILE - 1) / SCAN_TILE;

    char* ws = (char*)d_ws;
    size_t offb = 0;
    auto alloc = [&](size_t bytes) -> void* {
        void* p = ws + offb; offb += (bytes + 255) & ~(size_t)255; return p;
    };
    int*   flags  = (int*)  alloc(256);
    int*   bsum   = (int*)  alloc(1024);
    uint4* wpk1   = (uint4*)alloc(16 * 128 * 16);         // 32 KB packed W1
    uint4* wpk2   = (uint4*)alloc(16 * 64 * 16);          // 16 KB packed W2
    int*   deg    = (int*)  alloc((size_t)M * 4);
    int*   off    = (int*)  alloc((size_t)(M + 1) * 4);
    int*   cursor = (int*)  alloc((size_t)M * 4);
    float* dinv   = (float*)alloc((size_t)M * 4);
    int*   eidx   = (int*)  alloc((size_t)E * 4);
    u16*   hs1    = (u16*)  alloc((size_t)M * 128 * 2);   // 25.6 MB
    u16*   out1   = (u16*)  alloc((size_t)M * 128 * 2);   // 25.6 MB
    u16*   hs2    = hs1;   // layer-2 hs reuses hs1 (dead after aggregate1)
    (void)ws_size; (void)n_in; (void)out_size;

    detect_k<<<1, 256, 0, stream>>>((const u32*)x, (const u32*)ei, flags);
    w_pack_k<128><<<8, 256, 0, stream>>>(W1, wpk1, flags);
    w_pack_k<64><<<4, 256, 0, stream>>>(W2, wpk2, flags);

    hipMemsetAsync(deg, 0, (size_t)M * 4, stream);
    count_deg_k<<<(E + 255) / 256, 256, 0, stream>>>(ei, E, flags, deg);
    scan_partial_k<<<NB, 256, 0, stream>>>(deg, M, bsum);
    scan_bsum_k<<<1, 256, 0, stream>>>(bsum, NB, off, M);
    scan_final_k<<<NB, 256, 0, stream>>>(deg, bsum, M, off, cursor, dinv);
    fill_k<<<(E + 255) / 256, 256, 0, stream>>>(ei, E, flags, cursor, eidx);

    // layer 1 (128 -> 128, relu)
    gemm_mfma_k<128><<<(M + 127) / 128, 256, 0, stream>>>(x, wpk1, dinv, hs1, flags, 1, M);
    aggregate_k<128, true><<<(M + 15) / 16, 256, 0, stream>>>(hs1, eidx, off, dinv, b1, out1,
                                                              flags, 0, M);
    // layer 2 (128 -> 64)
    gemm_mfma_k<64><<<(M + 127) / 128, 256, 0, stream>>>(out1, wpk2, dinv, hs2, flags, 0, M);
    aggregate_k<64, false><<<(M + 31) / 32, 256, 0, stream>>>(hs2, eidx, off, dinv, b2, d_out,
                                                              flags, 1, M);
}